// Round 7
// baseline (706.064 us; speedup 1.0000x reference)
//
#include <hip/hip_runtime.h>
#include <hip/hip_bf16.h>

#define N_NODES 20000
#define N_EDGES 320000
#define HD 512
#define NPART 5000   // agg blocks = pool partials

typedef __attribute__((ext_vector_type(8))) short bf16x8;
typedef __attribute__((ext_vector_type(4))) float f32x4;

// ---------- bf16 helpers (RNE pack, cheap unpack) ----------
__device__ inline ushort f2bf(float f) {
    uint u = __float_as_uint(f);
    uint r = (u + 0x7fffu + ((u >> 16) & 1u)) >> 16;
    return (ushort)r;
}
__device__ inline uint pack2(float a, float b) {
    return (uint)f2bf(a) | ((uint)f2bf(b) << 16);
}
__device__ inline float bflo(uint u) { return __uint_as_float(u << 16); }
__device__ inline float bfhi(uint u) { return __uint_as_float(u & 0xffff0000u); }

// ---------- fused prep: x->bf16 | W1/2/3 -> Wt bf16 | zero deg ----------
#define NB_CVT 5000
#define NB_WT  192
#define NB_ZD  79
__global__ __launch_bounds__(256) void prep_k(const float* __restrict__ x,
                                              ushort* __restrict__ xb,
                                              const float* __restrict__ W1,
                                              const float* __restrict__ W2,
                                              const float* __restrict__ W3,
                                              ushort* __restrict__ T1,
                                              ushort* __restrict__ T2,
                                              ushort* __restrict__ T3,
                                              int* __restrict__ deg) {
    __shared__ float t[64][65];
    const int b = blockIdx.x;
    const int tid = threadIdx.x;
    if (b < NB_CVT) {
        int c = b * 256 + tid;
        const float4* p = (const float4*)x + (size_t)c * 2;
        float4 a = p[0], q = p[1];
        uint4 o;
        o.x = pack2(a.x, a.y); o.y = pack2(a.z, a.w);
        o.z = pack2(q.x, q.y); o.w = pack2(q.z, q.w);
        ((uint4*)xb)[c] = o;
    } else if (b < NB_CVT + NB_WT) {
        int idx = b - NB_CVT;
        int layer = idx >> 6, rem = idx & 63;
        const float* W = (layer == 0) ? W1 : (layer == 1) ? W2 : W3;
        ushort* T      = (layer == 0) ? T1 : (layer == 1) ? T2 : T3;
        int kb = (rem >> 3) * 64, nb = (rem & 7) * 64;
        int c = tid & 63, r4 = tid >> 6;
        #pragma unroll
        for (int l = 0; l < 16; ++l) {
            int r = l * 4 + r4;
            t[r][c] = W[(size_t)(kb + r) * HD + nb + c];
        }
        __syncthreads();
        #pragma unroll
        for (int l = 0; l < 16; ++l) {
            int r = l * 4 + r4;
            T[(size_t)(nb + r) * HD + kb + c] = f2bf(t[c][r]);
        }
    } else {
        int i = (b - NB_CVT - NB_WT) * 256 + tid;
        if (i < N_NODES) deg[i] = 0;
    }
}

// ---------- bf16 MFMA GEMM: C[M,512] = A[M,512] * Bt[n][k]^T ----------
#define LDSK 40   // 32 + 8 pad: frag ds_read_b128 -> 2-way bank alias = free
__global__ __launch_bounds__(256) void gemm_bf16_k(const ushort* __restrict__ A,
                                                   const ushort* __restrict__ Bt,
                                                   ushort* __restrict__ C, int M) {
    __shared__ __align__(16) short As[128 * LDSK];
    __shared__ __align__(16) short Bs[128 * LDSK];
    const int tid = threadIdx.x;
    const int lane = tid & 63;
    const int wave = tid >> 6;
    const int l15 = lane & 15;
    const int q = lane >> 4;
    const int wrow = wave >> 1, wcol = wave & 1;
    const int row0 = blockIdx.y * 128;
    const int col0 = blockIdx.x * 128;

    f32x4 acc[4][4] = {};

    for (int k0 = 0; k0 < HD; k0 += 32) {
        #pragma unroll
        for (int l = 0; l < 2; ++l) {
            int c = tid + l * 256;          // 512 chunks of 8 bf16
            int row = c >> 2, kc = c & 3;
            uint4 v = make_uint4(0u, 0u, 0u, 0u);
            int gr = row0 + row;
            if (gr < M) v = *(const uint4*)&A[(size_t)gr * HD + k0 + kc * 8];
            *(uint4*)&As[row * LDSK + kc * 8] = v;
            uint4 w = *(const uint4*)&Bt[(size_t)(col0 + row) * HD + k0 + kc * 8];
            *(uint4*)&Bs[row * LDSK + kc * 8] = w;
        }
        __syncthreads();
        bf16x8 aF[4], bF[4];
        #pragma unroll
        for (int i = 0; i < 4; ++i)
            aF[i] = *(bf16x8*)&As[(wrow * 64 + i * 16 + l15) * LDSK + q * 8];
        #pragma unroll
        for (int j = 0; j < 4; ++j)
            bF[j] = *(bf16x8*)&Bs[(wcol * 64 + j * 16 + l15) * LDSK + q * 8];
        #pragma unroll
        for (int i = 0; i < 4; ++i)
            #pragma unroll
            for (int j = 0; j < 4; ++j)
                acc[i][j] = __builtin_amdgcn_mfma_f32_16x16x32_bf16(aF[i], bF[j], acc[i][j], 0, 0, 0);
        __syncthreads();
    }
    #pragma unroll
    for (int i = 0; i < 4; ++i) {
        #pragma unroll
        for (int r = 0; r < 4; ++r) {
            int gr = row0 + wrow * 64 + i * 16 + q * 4 + r;
            if (gr < M) {
                #pragma unroll
                for (int j = 0; j < 4; ++j) {
                    int gc = col0 + wcol * 64 + j * 16 + l15;
                    C[(size_t)gr * HD + gc] = f2bf(acc[i][j][r]);
                }
            }
        }
    }
}

// ---------- CSR build ----------
__global__ void hist_k(const int* __restrict__ rows, int* __restrict__ deg) {
    int e = blockIdx.x * blockDim.x + threadIdx.x;
    if (e < N_EDGES) atomicAdd(&deg[rows[e]], 1);
}

// one workgroup, 16 waves, shuffle-scan
__global__ __launch_bounds__(1024) void scan_k(const int* __restrict__ deg,
                                               int* __restrict__ rowstart,
                                               int* __restrict__ cursor) {
    __shared__ int wsum[16];
    const int tid = threadIdx.x;
    const int lane = tid & 63, wv = tid >> 6;
    int carry = 0;
    for (int base = 0; base < N_NODES; base += 1024) {
        int i = base + tid;
        int v = (i < N_NODES) ? deg[i] : 0;
        int incl = v;
        #pragma unroll
        for (int off = 1; off < 64; off <<= 1) {
            int t = __shfl_up(incl, off, 64);
            if (lane >= off) incl += t;
        }
        if (lane == 63) wsum[wv] = incl;
        __syncthreads();
        int woff = 0, tot = 0;
        #pragma unroll
        for (int w = 0; w < 16; ++w) {
            int sv = wsum[w];
            if (w < wv) woff += sv;
            tot += sv;
        }
        if (i < N_NODES) {
            int ex = carry + woff + incl - v;
            rowstart[i] = ex;
            cursor[i]   = ex;
        }
        carry += tot;
        __syncthreads();
    }
    if (tid == 0) rowstart[N_NODES] = carry;
}

__global__ void fill_k(const int* __restrict__ rows, const int* __restrict__ cols,
                       const float* __restrict__ vals, int* __restrict__ cursor,
                       int* __restrict__ csr_col, float* __restrict__ csr_val) {
    int e = blockIdx.x * blockDim.x + threadIdx.x;
    if (e < N_EDGES) {
        int p = atomicAdd(&cursor[rows[e]], 1);
        csr_col[p] = cols[e];
        csr_val[p] = vals[e];
    }
}

// ---------- aggregate + pool-partial (LDS combine, coalesced partial write) --
__device__ inline void fma8(float* acc, uint4 v, float w) {
    acc[0] += w * bflo(v.x); acc[1] += w * bfhi(v.x);
    acc[2] += w * bflo(v.y); acc[3] += w * bfhi(v.y);
    acc[4] += w * bflo(v.z); acc[5] += w * bfhi(v.z);
    acc[6] += w * bflo(v.w); acc[7] += w * bfhi(v.w);
}

__global__ __launch_bounds__(256) void agg_k(const ushort* __restrict__ s,
                                             const int* __restrict__ rowstart,
                                             const int* __restrict__ csr_col,
                                             const float* __restrict__ csr_val,
                                             const float* __restrict__ bias,
                                             ushort* __restrict__ hout,
                                             float* __restrict__ pm,
                                             float* __restrict__ ps) {
    __shared__ int   lm[512];
    __shared__ float ls[512];
    const int tid = threadIdx.x;
    lm[tid] = 0;       lm[tid + 256] = 0;       // float 0.0 bits
    ls[tid] = 0.f;     ls[tid + 256] = 0.f;
    __syncthreads();

    const int wave = tid >> 6, lane = tid & 63;
    const int r = blockIdx.x * 4 + wave;
    const uint4* s4 = (const uint4*)s;
    float acc[8] = {};
    const int beg = rowstart[r], end = rowstart[r + 1];
    int j = beg;
    for (; j + 4 <= end; j += 4) {
        int   c0 = csr_col[j],     c1 = csr_col[j + 1];
        int   c2 = csr_col[j + 2], c3 = csr_col[j + 3];
        float w0 = csr_val[j],     w1 = csr_val[j + 1];
        float w2 = csr_val[j + 2], w3 = csr_val[j + 3];
        uint4 v0 = s4[(size_t)c0 * 64 + lane];
        uint4 v1 = s4[(size_t)c1 * 64 + lane];
        uint4 v2 = s4[(size_t)c2 * 64 + lane];
        uint4 v3 = s4[(size_t)c3 * 64 + lane];
        fma8(acc, v0, w0);
        fma8(acc, v1, w1);
        fma8(acc, v2, w2);
        fma8(acc, v3, w3);
    }
    for (; j < end; ++j) {
        int   c0 = csr_col[j];
        float w0 = csr_val[j];
        uint4 v0 = s4[(size_t)c0 * 64 + lane];
        fma8(acc, v0, w0);
    }
    float4 b0 = ((const float4*)bias)[lane * 2];
    float4 b1 = ((const float4*)bias)[lane * 2 + 1];
    float o[8];
    o[0] = fmaxf(acc[0] + b0.x, 0.f); o[1] = fmaxf(acc[1] + b0.y, 0.f);
    o[2] = fmaxf(acc[2] + b0.z, 0.f); o[3] = fmaxf(acc[3] + b0.w, 0.f);
    o[4] = fmaxf(acc[4] + b1.x, 0.f); o[5] = fmaxf(acc[5] + b1.y, 0.f);
    o[6] = fmaxf(acc[6] + b1.z, 0.f); o[7] = fmaxf(acc[7] + b1.w, 0.f);
    uint4 ov;
    ov.x = pack2(o[0], o[1]); ov.y = pack2(o[2], o[3]);
    ov.z = pack2(o[4], o[5]); ov.w = pack2(o[6], o[7]);
    ((uint4*)hout)[(size_t)r * 64 + lane] = ov;

    // pool partial: LDS combine across 4 waves (4-way RMW, bank-parallel)
    const int cb = lane * 8;
    #pragma unroll
    for (int i = 0; i < 8; ++i) {
        atomicMax(&lm[cb + i], __float_as_int(o[i]));  // values >= 0
        atomicAdd(&ls[cb + i], o[i]);
    }
    __syncthreads();
    const size_t pb = (size_t)blockIdx.x * 512;
    pm[pb + tid]       = __int_as_float(lm[tid]);
    pm[pb + tid + 256] = __int_as_float(lm[tid + 256]);
    ps[pb + tid]       = ls[tid];
    ps[pb + tid + 256] = ls[tid + 256];
}

// ---------- reduce pool partials: [NPART][512] -> [512] max / sum ----------
// 256 blocks: b<128 -> max over pm, else sum over ps; 4 channels/block.
__global__ __launch_bounds__(256) void reduce_k(const float* __restrict__ pm,
                                                const float* __restrict__ ps,
                                                float* __restrict__ gm,
                                                float* __restrict__ gs) {
    __shared__ float red[256];
    const int b = blockIdx.x;
    const bool ismax = b < 128;
    const float* src = ismax ? pm : ps;
    const int cb = (b & 127) * 4;
    const int t = threadIdx.x;
    const int ch = cb + (t & 3);
    float acc = 0.f;
    #pragma unroll 4
    for (int p = (t >> 2); p < NPART; p += 64) {
        float v = src[(size_t)p * 512 + ch];
        acc = ismax ? fmaxf(acc, v) : (acc + v);
    }
    red[t] = acc;
    __syncthreads();
    if (t < 64) {
        float a = red[t];
        if (ismax) {
            a = fmaxf(a, red[t + 64]); a = fmaxf(a, red[t + 128]);
            a = fmaxf(a, red[t + 192]);
        } else {
            a += red[t + 64] + red[t + 128] + red[t + 192];
        }
        red[t] = a;
    }
    __syncthreads();
    if (t < 4) {
        float a = red[t];
        #pragma unroll
        for (int i = 1; i < 16; ++i) {
            float v = red[t + i * 4];
            a = ismax ? fmaxf(a, v) : (a + v);
        }
        if (ismax) gm[cb + t] = a; else gs[cb + t] = a;
    }
}

// ---------- head MLP + log_softmax ----------
__global__ __launch_bounds__(256) void mlp_k(const float* __restrict__ pool_max,
                                             const float* __restrict__ pool_sum,
                                             const float* __restrict__ l1W,
                                             const float* __restrict__ l1b,
                                             const float* __restrict__ l2W,
                                             const float* __restrict__ l2b,
                                             const float* __restrict__ l3W,
                                             const float* __restrict__ l3b,
                                             float* __restrict__ out) {
    __shared__ float g[1024];
    __shared__ float h1[256];
    __shared__ float a1[128];
    __shared__ float a2[64];
    __shared__ float a3[10];
    const int tid = threadIdx.x;
    for (int c = tid; c < 512; c += 256) {
        g[c]       = pool_max[c] + pool_max[512 + c] + pool_max[1024 + c];
        g[512 + c] = (pool_sum[c] + pool_sum[512 + c] + pool_sum[1024 + c]) *
                     (1.0f / N_NODES);
    }
    __syncthreads();
    {   // layer1 128 outputs, 2-way split-k across 256 threads
        int ch = tid & 127, half = tid >> 7;
        float acc = half ? 0.f : l1b[ch];
        int k0 = half * 512;
        for (int k = k0; k < k0 + 512; ++k) acc += g[k] * l1W[k * 128 + ch];
        h1[tid] = acc;
    }
    __syncthreads();
    if (tid < 128) a1[tid] = fmaxf(h1[tid] + h1[tid + 128], 0.f);
    __syncthreads();
    if (tid < 64) {
        float acc = l2b[tid];
        for (int k = 0; k < 128; ++k) acc += a1[k] * l2W[k * 64 + tid];
        a2[tid] = fmaxf(acc, 0.f);
    }
    __syncthreads();
    if (tid < 10) {
        float acc = l3b[tid];
        for (int k = 0; k < 64; ++k) acc += a2[k] * l3W[k * 10 + tid];
        a3[tid] = acc;
    }
    __syncthreads();
    if (tid == 0) {
        float m = a3[0];
        for (int j = 1; j < 10; ++j) m = fmaxf(m, a3[j]);
        float ssum = 0.f;
        for (int j = 0; j < 10; ++j) ssum += expf(a3[j] - m);
        float lse = m + logf(ssum);
        for (int j = 0; j < 10; ++j) out[j] = a3[j] - lse;
    }
}

extern "C" void kernel_launch(void* const* d_in, const int* in_sizes, int n_in,
                              void* d_out, int out_size, void* d_ws, size_t ws_size,
                              hipStream_t stream) {
    const float* x    = (const float*)d_in[0];
    const int*   rows = (const int*)  d_in[1];
    const int*   cols = (const int*)  d_in[2];
    const float* vals = (const float*)d_in[3];
    const float* W1   = (const float*)d_in[4];
    const float* b1   = (const float*)d_in[5];
    const float* W2   = (const float*)d_in[6];
    const float* b2   = (const float*)d_in[7];
    const float* W3   = (const float*)d_in[8];
    const float* b3   = (const float*)d_in[9];
    const float* l1W  = (const float*)d_in[10];
    const float* l1b  = (const float*)d_in[11];
    const float* l2W  = (const float*)d_in[12];
    const float* l2b  = (const float*)d_in[13];
    const float* l3W  = (const float*)d_in[14];
    const float* l3b  = (const float*)d_in[15];
    float* out = (float*)d_out;

    char* ws = (char*)d_ws;
    size_t off = 0;
    auto alloc = [&](size_t bytes) {
        void* p = ws + off;
        off += (bytes + 255) & ~(size_t)255;
        return p;
    };
    ushort* xb       = (ushort*)alloc((size_t)N_NODES * HD * 2);
    ushort* s        = (ushort*)alloc((size_t)N_NODES * HD * 2);
    ushort* hb       = (ushort*)alloc((size_t)N_NODES * HD * 2);
    ushort* wt1      = (ushort*)alloc((size_t)HD * HD * 2);
    ushort* wt2      = (ushort*)alloc((size_t)HD * HD * 2);
    ushort* wt3      = (ushort*)alloc((size_t)HD * HD * 2);
    int*    deg      = (int*)   alloc((size_t)N_NODES * 4);
    float*  gmax     = (float*) alloc((size_t)3 * 512 * 4);
    float*  gsum     = (float*) alloc((size_t)3 * 512 * 4);
    int*    rowstart = (int*)   alloc((size_t)(N_NODES + 1) * 4);
    int*    cursor   = (int*)   alloc((size_t)N_NODES * 4);
    int*    csr_col  = (int*)   alloc((size_t)N_EDGES * 4);
    float*  csr_val  = (float*) alloc((size_t)N_EDGES * 4);
    float*  pm       = (float*) alloc((size_t)NPART * 512 * 4);   // 10.24 MB
    float*  ps       = (float*) alloc((size_t)NPART * 512 * 4);   // 10.24 MB
    (void)ws_size; (void)in_sizes; (void)n_in; (void)out_size;

    // prep: cvt + wt + zero deg
    prep_k<<<NB_CVT + NB_WT + NB_ZD, 256, 0, stream>>>(
        x, xb, W1, W2, W3, wt1, wt2, wt3, deg);
    const int EB = (N_EDGES + 255) / 256;
    hist_k<<<EB, 256, 0, stream>>>(rows, deg);
    scan_k<<<1, 1024, 0, stream>>>(deg, rowstart, cursor);
    fill_k<<<EB, 256, 0, stream>>>(rows, cols, vals, cursor, csr_col, csr_val);

    dim3 ggrid(HD / 128, (N_NODES + 127) / 128);
    const int AB = N_NODES / 4;   // == NPART

    // layer 1
    gemm_bf16_k<<<ggrid, 256, 0, stream>>>(xb, wt1, s, N_NODES);
    agg_k<<<AB, 256, 0, stream>>>(s, rowstart, csr_col, csr_val, b1, hb, pm, ps);
    reduce_k<<<256, 256, 0, stream>>>(pm, ps, gmax, gsum);

    // layer 2
    gemm_bf16_k<<<ggrid, 256, 0, stream>>>(hb, wt2, s, N_NODES);
    agg_k<<<AB, 256, 0, stream>>>(s, rowstart, csr_col, csr_val, b2, hb, pm, ps);
    reduce_k<<<256, 256, 0, stream>>>(pm, ps, gmax + 512, gsum + 512);

    // layer 3
    gemm_bf16_k<<<ggrid, 256, 0, stream>>>(hb, wt3, s, N_NODES);
    agg_k<<<AB, 256, 0, stream>>>(s, rowstart, csr_col, csr_val, b3, hb, pm, ps);
    reduce_k<<<256, 256, 0, stream>>>(pm, ps, gmax + 1024, gsum + 1024);

    mlp_k<<<1, 256, 0, stream>>>(gmax, gsum, l1W, l1b, l2W, l2b, l3W, l3b, out);
}

// Round 8
// 473.939 us; speedup vs baseline: 1.4898x; 1.4898x over previous
//
#include <hip/hip_runtime.h>
#include <hip/hip_bf16.h>

#define N_NODES 20000
#define N_EDGES 320000
#define HD 512

typedef __attribute__((ext_vector_type(8))) short bf16x8;
typedef __attribute__((ext_vector_type(4))) float f32x4;

// ---------- bf16 helpers (RNE pack, cheap unpack) ----------
__device__ inline ushort f2bf(float f) {
    uint u = __float_as_uint(f);
    uint r = (u + 0x7fffu + ((u >> 16) & 1u)) >> 16;
    return (ushort)r;
}
__device__ inline uint pack2(float a, float b) {
    return (uint)f2bf(a) | ((uint)f2bf(b) << 16);
}
__device__ inline float bflo(uint u) { return __uint_as_float(u << 16); }
__device__ inline float bfhi(uint u) { return __uint_as_float(u & 0xffff0000u); }

// async global->LDS, 16B per lane; LDS dest = wave-uniform base + lane*16
__device__ __forceinline__ void async_load16(const void* g, void* l) {
    __builtin_amdgcn_global_load_lds(
        (const __attribute__((address_space(1))) uint*)g,
        (__attribute__((address_space(3))) uint*)l,
        16, 0, 0);
}

// ---------- fused prep: x->bf16 | W1/2/3 -> Wt bf16 | zero deg/pmax/psum ----
#define NB_CVT 5000
#define NB_WT  192
#define NB_ZD  79
__global__ __launch_bounds__(256) void prep_k(const float* __restrict__ x,
                                              ushort* __restrict__ xb,
                                              const float* __restrict__ W1,
                                              const float* __restrict__ W2,
                                              const float* __restrict__ W3,
                                              ushort* __restrict__ T1,
                                              ushort* __restrict__ T2,
                                              ushort* __restrict__ T3,
                                              int* __restrict__ deg,
                                              float* __restrict__ pmax,
                                              float* __restrict__ psum) {
    __shared__ float t[64][65];
    const int b = blockIdx.x;
    const int tid = threadIdx.x;
    if (b < NB_CVT) {
        int c = b * 256 + tid;
        const float4* p = (const float4*)x + (size_t)c * 2;
        float4 a = p[0], q = p[1];
        uint4 o;
        o.x = pack2(a.x, a.y); o.y = pack2(a.z, a.w);
        o.z = pack2(q.x, q.y); o.w = pack2(q.z, q.w);
        ((uint4*)xb)[c] = o;
    } else if (b < NB_CVT + NB_WT) {
        int idx = b - NB_CVT;
        int layer = idx >> 6, rem = idx & 63;
        const float* W = (layer == 0) ? W1 : (layer == 1) ? W2 : W3;
        ushort* T      = (layer == 0) ? T1 : (layer == 1) ? T2 : T3;
        int kb = (rem >> 3) * 64, nb = (rem & 7) * 64;
        int c = tid & 63, r4 = tid >> 6;
        #pragma unroll
        for (int l = 0; l < 16; ++l) {
            int r = l * 4 + r4;
            t[r][c] = W[(size_t)(kb + r) * HD + nb + c];
        }
        __syncthreads();
        #pragma unroll
        for (int l = 0; l < 16; ++l) {
            int r = l * 4 + r4;
            T[(size_t)(nb + r) * HD + kb + c] = f2bf(t[c][r]);
        }
    } else if (b < NB_CVT + NB_WT + NB_ZD) {
        int i = (b - NB_CVT - NB_WT) * 256 + tid;
        if (i < N_NODES) deg[i] = 0;
    } else if (b < NB_CVT + NB_WT + NB_ZD + 6) {
        int i = (b - NB_CVT - NB_WT - NB_ZD) * 256 + tid;   // 1536 floats
        pmax[i] = 0.f;
    } else {
        int i = (b - NB_CVT - NB_WT - NB_ZD - 6) * 256 + tid;
        psum[i] = 0.f;
    }
}

// ---------- bf16 MFMA GEMM with global_load_lds staging ----------
// LDS layout: [128 rows][32 shorts], UNPADDED (required by global_load_lds).
// Bank-conflict fix: chunk kc of row r stored at slot kc ^ ((r>>1)&3)
// (applied on the global-address side), undone at fragment read.
#define LDSK 32
__global__ __launch_bounds__(256) void gemm_bf16_k(const ushort* __restrict__ A,
                                                   const ushort* __restrict__ Bt,
                                                   ushort* __restrict__ C, int M) {
    __shared__ __align__(16) short As[128 * LDSK];
    __shared__ __align__(16) short Bs[128 * LDSK];
    const int tid = threadIdx.x;
    const int lane = tid & 63;
    const int wave = tid >> 6;
    const int l15 = lane & 15;
    const int q = lane >> 4;
    const int wrow = wave >> 1, wcol = wave & 1;
    const int row0 = blockIdx.y * 128;
    const int col0 = blockIdx.x * 128;

    // staging: lane -> (row srow in 16-row group, swizzled chunk kc)
    const int srow = lane >> 2;
    const int kc   = (lane & 3) ^ ((lane >> 3) & 3);
    // fragment read: slot = q ^ ((l15>>1)&3)
    const int sl = (l15 >> 1) & 3;

    f32x4 acc[4][4] = {};

    for (int k0 = 0; k0 < HD; k0 += 32) {
        #pragma unroll
        for (int l = 0; l < 2; ++l) {
            const int rbase = wave * 32 + l * 16;       // wave-uniform
            const ushort* ga = &A [(size_t)(row0 + rbase + srow) * HD + k0 + kc * 8];
            const ushort* gb = &Bt[(size_t)(col0 + rbase + srow) * HD + k0 + kc * 8];
            async_load16(ga, &As[rbase * LDSK]);
            async_load16(gb, &Bs[rbase * LDSK]);
        }
        __syncthreads();
        bf16x8 aF[4], bF[4];
        #pragma unroll
        for (int i = 0; i < 4; ++i)
            aF[i] = *(bf16x8*)&As[(wrow * 64 + i * 16 + l15) * LDSK + (q ^ sl) * 8];
        #pragma unroll
        for (int j = 0; j < 4; ++j)
            bF[j] = *(bf16x8*)&Bs[(wcol * 64 + j * 16 + l15) * LDSK + (q ^ sl) * 8];
        #pragma unroll
        for (int i = 0; i < 4; ++i)
            #pragma unroll
            for (int j = 0; j < 4; ++j)
                acc[i][j] = __builtin_amdgcn_mfma_f32_16x16x32_bf16(aF[i], bF[j], acc[i][j], 0, 0, 0);
        __syncthreads();
    }
    #pragma unroll
    for (int i = 0; i < 4; ++i) {
        #pragma unroll
        for (int r = 0; r < 4; ++r) {
            int gr = row0 + wrow * 64 + i * 16 + q * 4 + r;
            if (gr < M) {
                #pragma unroll
                for (int j = 0; j < 4; ++j) {
                    int gc = col0 + wcol * 64 + j * 16 + l15;
                    C[(size_t)gr * HD + gc] = f2bf(acc[i][j][r]);
                }
            }
        }
    }
}

// ---------- CSR build ----------
__global__ void hist_k(const int* __restrict__ rows, int* __restrict__ deg) {
    int e = blockIdx.x * blockDim.x + threadIdx.x;
    if (e < N_EDGES) atomicAdd(&deg[rows[e]], 1);
}

// one workgroup, 16 waves, shuffle-scan
__global__ __launch_bounds__(1024) void scan_k(const int* __restrict__ deg,
                                               int* __restrict__ rowstart,
                                               int* __restrict__ cursor) {
    __shared__ int wsum[16];
    const int tid = threadIdx.x;
    const int lane = tid & 63, wv = tid >> 6;
    int carry = 0;
    for (int base = 0; base < N_NODES; base += 1024) {
        int i = base + tid;
        int v = (i < N_NODES) ? deg[i] : 0;
        int incl = v;
        #pragma unroll
        for (int off = 1; off < 64; off <<= 1) {
            int t = __shfl_up(incl, off, 64);
            if (lane >= off) incl += t;
        }
        if (lane == 63) wsum[wv] = incl;
        __syncthreads();
        int woff = 0, tot = 0;
        #pragma unroll
        for (int w = 0; w < 16; ++w) {
            int sv = wsum[w];
            if (w < wv) woff += sv;
            tot += sv;
        }
        if (i < N_NODES) {
            int ex = carry + woff + incl - v;
            rowstart[i] = ex;
            cursor[i]   = ex;
        }
        carry += tot;
        __syncthreads();
    }
    if (tid == 0) rowstart[N_NODES] = carry;
}

__global__ void fill_k(const int* __restrict__ rows, const int* __restrict__ cols,
                       const float* __restrict__ vals, int* __restrict__ cursor,
                       int* __restrict__ csr_col, float* __restrict__ csr_val) {
    int e = blockIdx.x * blockDim.x + threadIdx.x;
    if (e < N_EDGES) {
        int p = atomicAdd(&cursor[rows[e]], 1);
        csr_col[p] = cols[e];
        csr_val[p] = vals[e];
    }
}

// ---------- aggregate (bf16 in/out, fp32 acc): one wave per row ----------
__device__ inline void fma8(float* acc, uint4 v, float w) {
    acc[0] += w * bflo(v.x); acc[1] += w * bfhi(v.x);
    acc[2] += w * bflo(v.y); acc[3] += w * bfhi(v.y);
    acc[4] += w * bflo(v.z); acc[5] += w * bfhi(v.z);
    acc[6] += w * bflo(v.w); acc[7] += w * bfhi(v.w);
}

__global__ __launch_bounds__(256) void agg_k(const ushort* __restrict__ s,
                                             const int* __restrict__ rowstart,
                                             const int* __restrict__ csr_col,
                                             const float* __restrict__ csr_val,
                                             const float* __restrict__ bias,
                                             ushort* __restrict__ hout) {
    const int wave = threadIdx.x >> 6, lane = threadIdx.x & 63;
    const int r = blockIdx.x * 4 + wave;
    const uint4* s4 = (const uint4*)s;
    float acc[8] = {};
    const int beg = rowstart[r], end = rowstart[r + 1];
    int j = beg;
    for (; j + 4 <= end; j += 4) {
        int   c0 = csr_col[j],     c1 = csr_col[j + 1];
        int   c2 = csr_col[j + 2], c3 = csr_col[j + 3];
        float w0 = csr_val[j],     w1 = csr_val[j + 1];
        float w2 = csr_val[j + 2], w3 = csr_val[j + 3];
        uint4 v0 = s4[(size_t)c0 * 64 + lane];
        uint4 v1 = s4[(size_t)c1 * 64 + lane];
        uint4 v2 = s4[(size_t)c2 * 64 + lane];
        uint4 v3 = s4[(size_t)c3 * 64 + lane];
        fma8(acc, v0, w0);
        fma8(acc, v1, w1);
        fma8(acc, v2, w2);
        fma8(acc, v3, w3);
    }
    for (; j < end; ++j) {
        int   c0 = csr_col[j];
        float w0 = csr_val[j];
        uint4 v0 = s4[(size_t)c0 * 64 + lane];
        fma8(acc, v0, w0);
    }
    float4 b0 = ((const float4*)bias)[lane * 2];
    float4 b1 = ((const float4*)bias)[lane * 2 + 1];
    float o[8];
    o[0] = fmaxf(acc[0] + b0.x, 0.f); o[1] = fmaxf(acc[1] + b0.y, 0.f);
    o[2] = fmaxf(acc[2] + b0.z, 0.f); o[3] = fmaxf(acc[3] + b0.w, 0.f);
    o[4] = fmaxf(acc[4] + b1.x, 0.f); o[5] = fmaxf(acc[5] + b1.y, 0.f);
    o[6] = fmaxf(acc[6] + b1.z, 0.f); o[7] = fmaxf(acc[7] + b1.w, 0.f);
    uint4 ov;
    ov.x = pack2(o[0], o[1]); ov.y = pack2(o[2], o[3]);
    ov.z = pack2(o[4], o[5]); ov.w = pack2(o[6], o[7]);
    ((uint4*)hout)[(size_t)r * 64 + lane] = ov;
}

// ---------- pool: per-channel max & sum (bf16 input), 256 blocks ----------
__global__ __launch_bounds__(256) void pool_k(const ushort* __restrict__ h,
                                              float* __restrict__ pmax,
                                              float* __restrict__ psum) {
    const int tid = threadIdx.x;
    const uint* h2 = (const uint*)h;
    float m0 = 0.f, m1 = 0.f, s0 = 0.f, s1 = 0.f;   // relu output >= 0
    for (int r = blockIdx.x; r < N_NODES; r += gridDim.x) {
        uint v = h2[(size_t)r * 256 + tid];
        float a = bflo(v), b = bfhi(v);
        m0 = fmaxf(m0, a); m1 = fmaxf(m1, b);
        s0 += a;           s1 += b;
    }
    atomicMax((int*)&pmax[tid * 2],     __float_as_int(m0));
    atomicMax((int*)&pmax[tid * 2 + 1], __float_as_int(m1));
    atomicAdd(&psum[tid * 2],     s0);
    atomicAdd(&psum[tid * 2 + 1], s1);
}

// ---------- head MLP + log_softmax ----------
__global__ __launch_bounds__(256) void mlp_k(const float* __restrict__ pool_max,
                                             const float* __restrict__ pool_sum,
                                             const float* __restrict__ l1W,
                                             const float* __restrict__ l1b,
                                             const float* __restrict__ l2W,
                                             const float* __restrict__ l2b,
                                             const float* __restrict__ l3W,
                                             const float* __restrict__ l3b,
                                             float* __restrict__ out) {
    __shared__ float g[1024];
    __shared__ float a1[128];
    __shared__ float a2[64];
    __shared__ float a3[10];
    const int tid = threadIdx.x;
    for (int c = tid; c < 512; c += 256) {
        g[c]       = pool_max[c] + pool_max[512 + c] + pool_max[1024 + c];
        g[512 + c] = (pool_sum[c] + pool_sum[512 + c] + pool_sum[1024 + c]) *
                     (1.0f / N_NODES);
    }
    __syncthreads();
    if (tid < 128) {
        float acc = l1b[tid];
        for (int k = 0; k < 1024; ++k) acc += g[k] * l1W[k * 128 + tid];
        a1[tid] = fmaxf(acc, 0.f);
    }
    __syncthreads();
    if (tid < 64) {
        float acc = l2b[tid];
        for (int k = 0; k < 128; ++k) acc += a1[k] * l2W[k * 64 + tid];
        a2[tid] = fmaxf(acc, 0.f);
    }
    __syncthreads();
    if (tid < 10) {
        float acc = l3b[tid];
        for (int k = 0; k < 64; ++k) acc += a2[k] * l3W[k * 10 + tid];
        a3[tid] = acc;
    }
    __syncthreads();
    if (tid == 0) {
        float m = a3[0];
        for (int j = 1; j < 10; ++j) m = fmaxf(m, a3[j]);
        float ssum = 0.f;
        for (int j = 0; j < 10; ++j) ssum += expf(a3[j] - m);
        float lse = m + logf(ssum);
        for (int j = 0; j < 10; ++j) out[j] = a3[j] - lse;
    }
}

extern "C" void kernel_launch(void* const* d_in, const int* in_sizes, int n_in,
                              void* d_out, int out_size, void* d_ws, size_t ws_size,
                              hipStream_t stream) {
    const float* x    = (const float*)d_in[0];
    const int*   rows = (const int*)  d_in[1];
    const int*   cols = (const int*)  d_in[2];
    const float* vals = (const float*)d_in[3];
    const float* W1   = (const float*)d_in[4];
    const float* b1   = (const float*)d_in[5];
    const float* W2   = (const float*)d_in[6];
    const float* b2   = (const float*)d_in[7];
    const float* W3   = (const float*)d_in[8];
    const float* b3   = (const float*)d_in[9];
    const float* l1W  = (const float*)d_in[10];
    const float* l1b  = (const float*)d_in[11];
    const float* l2W  = (const float*)d_in[12];
    const float* l2b  = (const float*)d_in[13];
    const float* l3W  = (const float*)d_in[14];
    const float* l3b  = (const float*)d_in[15];
    float* out = (float*)d_out;

    char* ws = (char*)d_ws;
    size_t off = 0;
    auto alloc = [&](size_t bytes) {
        void* p = ws + off;
        off += (bytes + 255) & ~(size_t)255;
        return p;
    };
    ushort* xb       = (ushort*)alloc((size_t)N_NODES * HD * 2);
    ushort* s        = (ushort*)alloc((size_t)N_NODES * HD * 2);
    ushort* hb       = (ushort*)alloc((size_t)N_NODES * HD * 2);
    ushort* wt1      = (ushort*)alloc((size_t)HD * HD * 2);
    ushort* wt2      = (ushort*)alloc((size_t)HD * HD * 2);
    ushort* wt3      = (ushort*)alloc((size_t)HD * HD * 2);
    int*    deg      = (int*)   alloc((size_t)N_NODES * 4);
    float*  pmax     = (float*) alloc((size_t)3 * 512 * 4);
    float*  psum     = (float*) alloc((size_t)3 * 512 * 4);
    int*    rowstart = (int*)   alloc((size_t)(N_NODES + 1) * 4);
    int*    cursor   = (int*)   alloc((size_t)N_NODES * 4);
    int*    csr_col  = (int*)   alloc((size_t)N_EDGES * 4);
    float*  csr_val  = (float*) alloc((size_t)N_EDGES * 4);
    (void)ws_size; (void)in_sizes; (void)n_in; (void)out_size;

    // prep: cvt + wt + zero (deg, pmax, psum)
    prep_k<<<NB_CVT + NB_WT + NB_ZD + 12, 256, 0, stream>>>(
        x, xb, W1, W2, W3, wt1, wt2, wt3, deg, pmax, psum);
    const int EB = (N_EDGES + 255) / 256;
    hist_k<<<EB, 256, 0, stream>>>(rows, deg);
    scan_k<<<1, 1024, 0, stream>>>(deg, rowstart, cursor);
    fill_k<<<EB, 256, 0, stream>>>(rows, cols, vals, cursor, csr_col, csr_val);

    dim3 ggrid(HD / 128, (N_NODES + 127) / 128);
    const int AB = N_NODES / 4;

    // layer 1
    gemm_bf16_k<<<ggrid, 256, 0, stream>>>(xb, wt1, s, N_NODES);
    agg_k<<<AB, 256, 0, stream>>>(s, rowstart, csr_col, csr_val, b1, hb);
    pool_k<<<256, 256, 0, stream>>>(hb, pmax, psum);

    // layer 2
    gemm_bf16_k<<<ggrid, 256, 0, stream>>>(hb, wt2, s, N_NODES);
    agg_k<<<AB, 256, 0, stream>>>(s, rowstart, csr_col, csr_val, b2, hb);
    pool_k<<<256, 256, 0, stream>>>(hb, pmax + 512, psum + 512);

    // layer 3
    gemm_bf16_k<<<ggrid, 256, 0, stream>>>(hb, wt3, s, N_NODES);
    agg_k<<<AB, 256, 0, stream>>>(s, rowstart, csr_col, csr_val, b3, hb);
    pool_k<<<256, 256, 0, stream>>>(hb, pmax + 1024, psum + 1024);

    mlp_k<<<1, 256, 0, stream>>>(pmax, psum, l1W, l1b, l2W, l2b, l3W, l3b, out);
}

// Round 9
// 423.431 us; speedup vs baseline: 1.6675x; 1.1193x over previous
//
#include <hip/hip_runtime.h>
#include <hip/hip_bf16.h>

#define N_NODES 20000
#define N_EDGES 320000
#define HD 512

typedef __attribute__((ext_vector_type(8))) short bf16x8;
typedef __attribute__((ext_vector_type(4))) float f32x4;

// ---------- bf16 helpers (RNE pack, cheap unpack) ----------
__device__ inline ushort f2bf(float f) {
    uint u = __float_as_uint(f);
    uint r = (u + 0x7fffu + ((u >> 16) & 1u)) >> 16;
    return (ushort)r;
}
__device__ inline uint pack2(float a, float b) {
    return (uint)f2bf(a) | ((uint)f2bf(b) << 16);
}
__device__ inline float bflo(uint u) { return __uint_as_float(u << 16); }
__device__ inline float bfhi(uint u) { return __uint_as_float(u & 0xffff0000u); }

// async global->LDS, 16B per lane; LDS dest = wave-uniform base + lane*16
__device__ __forceinline__ void async_load16(const void* g, void* l) {
    __builtin_amdgcn_global_load_lds(
        (const __attribute__((address_space(1))) uint*)g,
        (__attribute__((address_space(3))) uint*)l,
        16, 0, 0);
}

// ---------- fused prep: x->bf16 | W1/2/3 -> Wt bf16 | zero deg/pmax/psum ----
#define NB_CVT 5000
#define NB_WT  192
#define NB_ZD  79
__global__ __launch_bounds__(256) void prep_k(const float* __restrict__ x,
                                              ushort* __restrict__ xb,
                                              const float* __restrict__ W1,
                                              const float* __restrict__ W2,
                                              const float* __restrict__ W3,
                                              ushort* __restrict__ T1,
                                              ushort* __restrict__ T2,
                                              ushort* __restrict__ T3,
                                              int* __restrict__ deg,
                                              float* __restrict__ pmax,
                                              float* __restrict__ psum) {
    __shared__ float t[64][65];
    const int b = blockIdx.x;
    const int tid = threadIdx.x;
    if (b < NB_CVT) {
        int c = b * 256 + tid;
        const float4* p = (const float4*)x + (size_t)c * 2;
        float4 a = p[0], q = p[1];
        uint4 o;
        o.x = pack2(a.x, a.y); o.y = pack2(a.z, a.w);
        o.z = pack2(q.x, q.y); o.w = pack2(q.z, q.w);
        ((uint4*)xb)[c] = o;
    } else if (b < NB_CVT + NB_WT) {
        int idx = b - NB_CVT;
        int layer = idx >> 6, rem = idx & 63;
        const float* W = (layer == 0) ? W1 : (layer == 1) ? W2 : W3;
        ushort* T      = (layer == 0) ? T1 : (layer == 1) ? T2 : T3;
        int kb = (rem >> 3) * 64, nb = (rem & 7) * 64;
        int c = tid & 63, r4 = tid >> 6;
        #pragma unroll
        for (int l = 0; l < 16; ++l) {
            int r = l * 4 + r4;
            t[r][c] = W[(size_t)(kb + r) * HD + nb + c];
        }
        __syncthreads();
        #pragma unroll
        for (int l = 0; l < 16; ++l) {
            int r = l * 4 + r4;
            T[(size_t)(nb + r) * HD + kb + c] = f2bf(t[c][r]);
        }
    } else if (b < NB_CVT + NB_WT + NB_ZD) {
        int i = (b - NB_CVT - NB_WT) * 256 + tid;
        if (i < N_NODES) deg[i] = 0;
    } else if (b < NB_CVT + NB_WT + NB_ZD + 6) {
        int i = (b - NB_CVT - NB_WT - NB_ZD) * 256 + tid;   // 1536 floats
        pmax[i] = 0.f;
    } else {
        int i = (b - NB_CVT - NB_WT - NB_ZD - 6) * 256 + tid;
        psum[i] = 0.f;
    }
}

// ---------- bf16 MFMA GEMM with global_load_lds staging ----------
// LDS layout: [128 rows][32 shorts], UNPADDED (required by global_load_lds).
// Bank-conflict fix: chunk kc of row r stored at slot kc ^ ((r>>1)&3)
// (applied on the global-address side), undone at fragment read.
#define LDSK 32
__global__ __launch_bounds__(256) void gemm_bf16_k(const ushort* __restrict__ A,
                                                   const ushort* __restrict__ Bt,
                                                   ushort* __restrict__ C, int M) {
    __shared__ __align__(16) short As[128 * LDSK];
    __shared__ __align__(16) short Bs[128 * LDSK];
    const int tid = threadIdx.x;
    const int lane = tid & 63;
    const int wave = tid >> 6;
    const int l15 = lane & 15;
    const int q = lane >> 4;
    const int wrow = wave >> 1, wcol = wave & 1;
    const int row0 = blockIdx.y * 128;
    const int col0 = blockIdx.x * 128;

    // staging: lane -> (row srow in 16-row group, swizzled chunk kc)
    const int srow = lane >> 2;
    const int kc   = (lane & 3) ^ ((lane >> 3) & 3);
    // fragment read: slot = q ^ ((l15>>1)&3)
    const int sl = (l15 >> 1) & 3;

    f32x4 acc[4][4] = {};

    for (int k0 = 0; k0 < HD; k0 += 32) {
        #pragma unroll
        for (int l = 0; l < 2; ++l) {
            const int rbase = wave * 32 + l * 16;       // wave-uniform
            const ushort* ga = &A [(size_t)(row0 + rbase + srow) * HD + k0 + kc * 8];
            const ushort* gb = &Bt[(size_t)(col0 + rbase + srow) * HD + k0 + kc * 8];
            async_load16(ga, &As[rbase * LDSK]);
            async_load16(gb, &Bs[rbase * LDSK]);
        }
        __syncthreads();
        bf16x8 aF[4], bF[4];
        #pragma unroll
        for (int i = 0; i < 4; ++i)
            aF[i] = *(bf16x8*)&As[(wrow * 64 + i * 16 + l15) * LDSK + (q ^ sl) * 8];
        #pragma unroll
        for (int j = 0; j < 4; ++j)
            bF[j] = *(bf16x8*)&Bs[(wcol * 64 + j * 16 + l15) * LDSK + (q ^ sl) * 8];
        #pragma unroll
        for (int i = 0; i < 4; ++i)
            #pragma unroll
            for (int j = 0; j < 4; ++j)
                acc[i][j] = __builtin_amdgcn_mfma_f32_16x16x32_bf16(aF[i], bF[j], acc[i][j], 0, 0, 0);
        __syncthreads();
    }
    #pragma unroll
    for (int i = 0; i < 4; ++i) {
        #pragma unroll
        for (int r = 0; r < 4; ++r) {
            int gr = row0 + wrow * 64 + i * 16 + q * 4 + r;
            if (gr < M) {
                #pragma unroll
                for (int j = 0; j < 4; ++j) {
                    int gc = col0 + wcol * 64 + j * 16 + l15;
                    C[(size_t)gr * HD + gc] = f2bf(acc[i][j][r]);
                }
            }
        }
    }
}

// ---------- CSR build ----------
__global__ void hist_k(const int* __restrict__ rows, int* __restrict__ deg) {
    int e = blockIdx.x * blockDim.x + threadIdx.x;
    if (e < N_EDGES) atomicAdd(&deg[rows[e]], 1);
}

// one workgroup, 16 waves, shuffle-scan
__global__ __launch_bounds__(1024) void scan_k(const int* __restrict__ deg,
                                               int* __restrict__ rowstart,
                                               int* __restrict__ cursor) {
    __shared__ int wsum[16];
    const int tid = threadIdx.x;
    const int lane = tid & 63, wv = tid >> 6;
    int carry = 0;
    for (int base = 0; base < N_NODES; base += 1024) {
        int i = base + tid;
        int v = (i < N_NODES) ? deg[i] : 0;
        int incl = v;
        #pragma unroll
        for (int off = 1; off < 64; off <<= 1) {
            int t = __shfl_up(incl, off, 64);
            if (lane >= off) incl += t;
        }
        if (lane == 63) wsum[wv] = incl;
        __syncthreads();
        int woff = 0, tot = 0;
        #pragma unroll
        for (int w = 0; w < 16; ++w) {
            int sv = wsum[w];
            if (w < wv) woff += sv;
            tot += sv;
        }
        if (i < N_NODES) {
            int ex = carry + woff + incl - v;
            rowstart[i] = ex;
            cursor[i]   = ex;
        }
        carry += tot;
        __syncthreads();
    }
    if (tid == 0) rowstart[N_NODES] = carry;
}

__global__ void fill_k(const int* __restrict__ rows, const int* __restrict__ cols,
                       const float* __restrict__ vals, int* __restrict__ cursor,
                       int* __restrict__ csr_col, float* __restrict__ csr_val) {
    int e = blockIdx.x * blockDim.x + threadIdx.x;
    if (e < N_EDGES) {
        int p = atomicAdd(&cursor[rows[e]], 1);
        csr_col[p] = cols[e];
        csr_val[p] = vals[e];
    }
}

// ---------- aggregate (bf16 in/out, fp32 acc): one wave per row ----------
__device__ inline void fma8(float* acc, uint4 v, float w) {
    acc[0] += w * bflo(v.x); acc[1] += w * bfhi(v.x);
    acc[2] += w * bflo(v.y); acc[3] += w * bfhi(v.y);
    acc[4] += w * bflo(v.z); acc[5] += w * bfhi(v.z);
    acc[6] += w * bflo(v.w); acc[7] += w * bfhi(v.w);
}

__global__ __launch_bounds__(256) void agg_k(const ushort* __restrict__ s,
                                             const int* __restrict__ rowstart,
                                             const int* __restrict__ csr_col,
                                             const float* __restrict__ csr_val,
                                             const float* __restrict__ bias,
                                             ushort* __restrict__ hout) {
    const int wave = threadIdx.x >> 6, lane = threadIdx.x & 63;
    const int r = blockIdx.x * 4 + wave;
    const uint4* s4 = (const uint4*)s;
    float acc[8] = {};
    const int beg = rowstart[r], end = rowstart[r + 1];
    int j = beg;
    for (; j + 4 <= end; j += 4) {
        int   c0 = csr_col[j],     c1 = csr_col[j + 1];
        int   c2 = csr_col[j + 2], c3 = csr_col[j + 3];
        float w0 = csr_val[j],     w1 = csr_val[j + 1];
        float w2 = csr_val[j + 2], w3 = csr_val[j + 3];
        uint4 v0 = s4[(size_t)c0 * 64 + lane];
        uint4 v1 = s4[(size_t)c1 * 64 + lane];
        uint4 v2 = s4[(size_t)c2 * 64 + lane];
        uint4 v3 = s4[(size_t)c3 * 64 + lane];
        fma8(acc, v0, w0);
        fma8(acc, v1, w1);
        fma8(acc, v2, w2);
        fma8(acc, v3, w3);
    }
    for (; j < end; ++j) {
        int   c0 = csr_col[j];
        float w0 = csr_val[j];
        uint4 v0 = s4[(size_t)c0 * 64 + lane];
        fma8(acc, v0, w0);
    }
    float4 b0 = ((const float4*)bias)[lane * 2];
    float4 b1 = ((const float4*)bias)[lane * 2 + 1];
    float o[8];
    o[0] = fmaxf(acc[0] + b0.x, 0.f); o[1] = fmaxf(acc[1] + b0.y, 0.f);
    o[2] = fmaxf(acc[2] + b0.z, 0.f); o[3] = fmaxf(acc[3] + b0.w, 0.f);
    o[4] = fmaxf(acc[4] + b1.x, 0.f); o[5] = fmaxf(acc[5] + b1.y, 0.f);
    o[6] = fmaxf(acc[6] + b1.z, 0.f); o[7] = fmaxf(acc[7] + b1.w, 0.f);
    uint4 ov;
    ov.x = pack2(o[0], o[1]); ov.y = pack2(o[2], o[3]);
    ov.z = pack2(o[4], o[5]); ov.w = pack2(o[6], o[7]);
    ((uint4*)hout)[(size_t)r * 64 + lane] = ov;
}

// ---------- pool: wave-per-row uint4 reads, LDS combine, 256 blocks ----------
__global__ __launch_bounds__(256) void pool_k(const ushort* __restrict__ h,
                                              float* __restrict__ pmax,
                                              float* __restrict__ psum) {
    __shared__ float lmx[4][512];
    __shared__ float lsm[4][512];
    const int tid = threadIdx.x;
    const int wave = tid >> 6, lane = tid & 63;
    const uint4* h4 = (const uint4*)h;      // row stride = 64 uint4
    float m[8] = {}, sm[8] = {};            // relu output >= 0
    for (int r = blockIdx.x * 4 + wave; r < N_NODES; r += gridDim.x * 4) {
        uint4 v = h4[(size_t)r * 64 + lane];
        m[0] = fmaxf(m[0], bflo(v.x)); sm[0] += bflo(v.x);
        m[1] = fmaxf(m[1], bfhi(v.x)); sm[1] += bfhi(v.x);
        m[2] = fmaxf(m[2], bflo(v.y)); sm[2] += bflo(v.y);
        m[3] = fmaxf(m[3], bfhi(v.y)); sm[3] += bfhi(v.y);
        m[4] = fmaxf(m[4], bflo(v.z)); sm[4] += bflo(v.z);
        m[5] = fmaxf(m[5], bfhi(v.z)); sm[5] += bfhi(v.z);
        m[6] = fmaxf(m[6], bflo(v.w)); sm[6] += bflo(v.w);
        m[7] = fmaxf(m[7], bfhi(v.w)); sm[7] += bfhi(v.w);
    }
    #pragma unroll
    for (int i = 0; i < 8; ++i) {
        lmx[wave][lane * 8 + i] = m[i];
        lsm[wave][lane * 8 + i] = sm[i];
    }
    __syncthreads();
    #pragma unroll
    for (int cc = 0; cc < 2; ++cc) {
        int ch = tid * 2 + cc;
        float mx = fmaxf(fmaxf(lmx[0][ch], lmx[1][ch]),
                         fmaxf(lmx[2][ch], lmx[3][ch]));
        float sv = (lsm[0][ch] + lsm[1][ch]) + (lsm[2][ch] + lsm[3][ch]);
        atomicMax((int*)&pmax[ch], __float_as_int(mx));
        atomicAdd(&psum[ch], sv);
    }
}

// ---------- head MLP + log_softmax (1024 threads, split-k) ----------
__global__ __launch_bounds__(1024) void mlp_k(const float* __restrict__ pool_max,
                                              const float* __restrict__ pool_sum,
                                              const float* __restrict__ l1W,
                                              const float* __restrict__ l1b,
                                              const float* __restrict__ l2W,
                                              const float* __restrict__ l2b,
                                              const float* __restrict__ l3W,
                                              const float* __restrict__ l3b,
                                              float* __restrict__ out) {
    __shared__ float g[1024];
    __shared__ float part[1024];
    __shared__ float a1[128];
    __shared__ float a2[64];
    __shared__ float a3[10];
    const int tid = threadIdx.x;
    if (tid < 512) {
        g[tid]       = pool_max[tid] + pool_max[512 + tid] + pool_max[1024 + tid];
        g[512 + tid] = (pool_sum[tid] + pool_sum[512 + tid] + pool_sum[1024 + tid]) *
                       (1.0f / N_NODES);
    }
    __syncthreads();
    {   // layer 1: 128 outputs, 8-way split-k (coalesced across ch)
        int ch = tid & 127, sl = tid >> 7;
        float acc = (sl == 0) ? l1b[ch] : 0.f;
        int k0 = sl * 128;
        #pragma unroll 4
        for (int k = k0; k < k0 + 128; ++k) acc += g[k] * l1W[k * 128 + ch];
        part[tid] = acc;
    }
    __syncthreads();
    if (tid < 128) {
        float a = part[tid];
        #pragma unroll
        for (int s = 1; s < 8; ++s) a += part[tid + s * 128];
        a1[tid] = fmaxf(a, 0.f);
    }
    __syncthreads();
    if (tid < 512) {   // layer 2: 64 outputs, 8-way split-k
        int ch = tid & 63, sl = tid >> 6;
        float acc = (sl == 0) ? l2b[ch] : 0.f;
        int k0 = sl * 16;
        #pragma unroll
        for (int k = k0; k < k0 + 16; ++k) acc += a1[k] * l2W[k * 64 + ch];
        part[tid] = acc;
    }
    __syncthreads();
    if (tid < 64) {
        float a = part[tid];
        #pragma unroll
        for (int s = 1; s < 8; ++s) a += part[tid + s * 64];
        a2[tid] = fmaxf(a, 0.f);
    }
    __syncthreads();
    if (tid < 10) {
        float acc = l3b[tid];
        for (int k = 0; k < 64; ++k) acc += a2[k] * l3W[k * 10 + tid];
        a3[tid] = acc;
    }
    __syncthreads();
    if (tid == 0) {
        float m = a3[0];
        for (int j = 1; j < 10; ++j) m = fmaxf(m, a3[j]);
        float ssum = 0.f;
        for (int j = 0; j < 10; ++j) ssum += expf(a3[j] - m);
        float lse = m + logf(ssum);
        for (int j = 0; j < 10; ++j) out[j] = a3[j] - lse;
    }
}

extern "C" void kernel_launch(void* const* d_in, const int* in_sizes, int n_in,
                              void* d_out, int out_size, void* d_ws, size_t ws_size,
                              hipStream_t stream) {
    const float* x    = (const float*)d_in[0];
    const int*   rows = (const int*)  d_in[1];
    const int*   cols = (const int*)  d_in[2];
    const float* vals = (const float*)d_in[3];
    const float* W1   = (const float*)d_in[4];
    const float* b1   = (const float*)d_in[5];
    const float* W2   = (const float*)d_in[6];
    const float* b2   = (const float*)d_in[7];
    const float* W3   = (const float*)d_in[8];
    const float* b3   = (const float*)d_in[9];
    const float* l1W  = (const float*)d_in[10];
    const float* l1b  = (const float*)d_in[11];
    const float* l2W  = (const float*)d_in[12];
    const float* l2b  = (const float*)d_in[13];
    const float* l3W  = (const float*)d_in[14];
    const float* l3b  = (const float*)d_in[15];
    float* out = (float*)d_out;

    char* ws = (char*)d_ws;
    size_t off = 0;
    auto alloc = [&](size_t bytes) {
        void* p = ws + off;
        off += (bytes + 255) & ~(size_t)255;
        return p;
    };
    ushort* xb       = (ushort*)alloc((size_t)N_NODES * HD * 2);
    ushort* s        = (ushort*)alloc((size_t)N_NODES * HD * 2);
    ushort* hb       = (ushort*)alloc((size_t)N_NODES * HD * 2);
    ushort* wt1      = (ushort*)alloc((size_t)HD * HD * 2);
    ushort* wt2      = (ushort*)alloc((size_t)HD * HD * 2);
    ushort* wt3      = (ushort*)alloc((size_t)HD * HD * 2);
    int*    deg      = (int*)   alloc((size_t)N_NODES * 4);
    float*  pmax     = (float*) alloc((size_t)3 * 512 * 4);
    float*  psum     = (float*) alloc((size_t)3 * 512 * 4);
    int*    rowstart = (int*)   alloc((size_t)(N_NODES + 1) * 4);
    int*    cursor   = (int*)   alloc((size_t)N_NODES * 4);
    int*    csr_col  = (int*)   alloc((size_t)N_EDGES * 4);
    float*  csr_val  = (float*) alloc((size_t)N_EDGES * 4);
    (void)ws_size; (void)in_sizes; (void)n_in; (void)out_size;

    // prep: cvt + wt + zero (deg, pmax, psum)
    prep_k<<<NB_CVT + NB_WT + NB_ZD + 12, 256, 0, stream>>>(
        x, xb, W1, W2, W3, wt1, wt2, wt3, deg, pmax, psum);
    const int EB = (N_EDGES + 255) / 256;
    hist_k<<<EB, 256, 0, stream>>>(rows, deg);
    scan_k<<<1, 1024, 0, stream>>>(deg, rowstart, cursor);
    fill_k<<<EB, 256, 0, stream>>>(rows, cols, vals, cursor, csr_col, csr_val);

    dim3 ggrid(HD / 128, (N_NODES + 127) / 128);
    const int AB = N_NODES / 4;

    // layer 1
    gemm_bf16_k<<<ggrid, 256, 0, stream>>>(xb, wt1, s, N_NODES);
    agg_k<<<AB, 256, 0, stream>>>(s, rowstart, csr_col, csr_val, b1, hb);
    pool_k<<<256, 256, 0, stream>>>(hb, pmax, psum);

    // layer 2
    gemm_bf16_k<<<ggrid, 256, 0, stream>>>(hb, wt2, s, N_NODES);
    agg_k<<<AB, 256, 0, stream>>>(s, rowstart, csr_col, csr_val, b2, hb);
    pool_k<<<256, 256, 0, stream>>>(hb, pmax + 512, psum + 512);

    // layer 3
    gemm_bf16_k<<<ggrid, 256, 0, stream>>>(hb, wt3, s, N_NODES);
    agg_k<<<AB, 256, 0, stream>>>(s, rowstart, csr_col, csr_val, b3, hb);
    pool_k<<<256, 256, 0, stream>>>(hb, pmax + 1024, psum + 1024);

    mlp_k<<<1, 1024, 0, stream>>>(pmax, psum, l1W, l1b, l2W, l2b, l3W, l3b, out);
}